// Round 11
// baseline (902.568 us; speedup 1.0000x reference)
//
#include <hip/hip_runtime.h>
#include <hip/hip_fp16.h>
#include <hip/hip_cooperative_groups.h>

typedef unsigned short u16;
typedef unsigned int   u32;
typedef _Float16 f16;
typedef __attribute__((ext_vector_type(8))) f16 f16x8;
typedef __attribute__((ext_vector_type(2))) f16 h2;
typedef __attribute__((ext_vector_type(4))) float f32x4;

#define NN 50000
#define EE 1600000
#define DD 128
#define DYY 64
#define NB 196      // dst buckets: dst>>8
#define EPB 8192    // edges per bucketing chunk
#define GB 196      // ceil(EE/EPB)
#define MAXD 160    // per-wave LDS edge cache
#define NTILE 3125  // 50000/16 row tiles (exact)
#define GMM 782     // ceil(NTILE/4)

namespace cg = cooperative_groups;

__device__ __forceinline__ u16 f2h(float f){
  union { f16 h; u16 u; } x; x.h = (f16)f; return x.u;
}
__device__ __forceinline__ float wave_sum(float v){
  #pragma unroll
  for (int s = 32; s; s >>= 1) v += __shfl_xor(v, s, 64);
  return v;
}

struct GParams {
  const int *src, *dst;
  const float *X0, *W1, *as1, *ad1, *b1, *W2, *as2, *ad2, *b2, *Wo, *bo;
  float* out;
  u16 *Hbf, *Abf, *srcs, *Wf1, *Wf2, *Wfo;
  u32* buf;
  float *Sv, *Dv;
  int *cnt, *offs, *btot, *bbase, *hist2d, *chunkbase;
};

// fp32 W[K=128][N=nct*16] -> fp16 MFMA B-fragment layout
__device__ __forceinline__ void wfrag_one(const float* __restrict__ W, u16* __restrict__ Wf,
                                          int nct, int s){
  int lane = s & 63;
  int t  = (s >> 6) % nct;
  int ks = (s >> 6) / nct;
  int q = lane >> 4, n = lane & 15;
  int N = nct * 16;
  u16 tmp[8];
  #pragma unroll
  for (int j = 0; j < 8; ++j)
    tmp[j] = f2h(W[(ks * 32 + q * 8 + j) * N + t * 16 + n]);
  *(uint4*)(Wf + (size_t)s * 8) = *(const uint4*)tmp;
}

__device__ __forceinline__ void stage_w(uint4* Wl, const u16* Wf, int n4, int tid){
  const uint4* Wg = (const uint4*)Wf;
  for (int i = tid; i < n4; i += 256) Wl[i] = Wg[i];
}

// MFMA GEMM tile body (W already staged in Wl): 4 row-tiles per block (one/wave),
// A-fragments from global, fused Sv/Dv epilogue. No block barriers inside.
__device__ void gemm_body(const void* __restrict__ X, int xf32, u16* __restrict__ Hout,
                          const float* __restrict__ as, const float* __restrict__ ad,
                          float* __restrict__ Sv, float* __restrict__ Dv,
                          int blk, int tid, const uint4* Wl){
  int wv = tid >> 6, lane = tid & 63;
  int rtile = blk * 4 + wv;
  if (rtile >= NTILE) return;
  int q = lane >> 4, n = lane & 15;
  int arow = rtile * 16 + n;
  f32x4 acc[8];
  #pragma unroll
  for (int t = 0; t < 8; ++t) acc[t] = (f32x4){0.f, 0.f, 0.f, 0.f};
  union F8 { uint4 u; f16x8 v; f16 h[8]; };
  #pragma unroll
  for (int ks = 0; ks < 4; ++ks){
    int kb = ks * 32 + q * 8;
    F8 a;
    if (!xf32){
      a.u = *(const uint4*)((const u16*)X + (size_t)arow * DD + kb);
    } else {
      const float* xp = (const float*)X + (size_t)arow * DD + kb;
      float4 f0 = *(const float4*)xp;
      float4 f1 = *(const float4*)(xp + 4);
      a.h[0] = (f16)f0.x; a.h[1] = (f16)f0.y; a.h[2] = (f16)f0.z; a.h[3] = (f16)f0.w;
      a.h[4] = (f16)f1.x; a.h[5] = (f16)f1.y; a.h[6] = (f16)f1.z; a.h[7] = (f16)f1.w;
    }
    #pragma unroll
    for (int t = 0; t < 8; ++t){
      F8 b; b.u = Wl[(ks * 8 + t) * 64 + lane];
      acc[t] = __builtin_amdgcn_mfma_f32_16x16x32_f16(a.v, b.v, acc[t], 0, 0, 0);
    }
  }
  float ps[4] = {0, 0, 0, 0}, pd[4] = {0, 0, 0, 0};
  #pragma unroll
  for (int t = 0; t < 8; ++t){
    float a_s = as[t * 16 + n];
    float a_d = ad[t * 16 + n];
    #pragma unroll
    for (int rg = 0; rg < 4; ++rg){
      ps[rg] += acc[t][rg] * a_s;
      pd[rg] += acc[t][rg] * a_d;
    }
  }
  #pragma unroll
  for (int rg = 0; rg < 4; ++rg){
    #pragma unroll
    for (int s = 1; s < 16; s <<= 1){
      ps[rg] += __shfl_xor(ps[rg], s, 64);
      pd[rg] += __shfl_xor(pd[rg], s, 64);
    }
  }
  #pragma unroll
  for (int rg = 0; rg < 4; ++rg){
    int grow = rtile * 16 + q * 4 + rg;
    if (n == 0){ Sv[grow] = ps[rg]; Dv[grow] = pd[rg]; }
    #pragma unroll
    for (int t = 0; t < 8; ++t)
      Hout[(size_t)grow * DD + t * 16 + n] = f2h(acc[t][rg]);
  }
}

// per-node aggregation (round-10 proven body; si/sw are this wave's LDS slices)
__device__ void agg_node(const u16* __restrict__ H, const float* __restrict__ Sv,
                         const float* __restrict__ Dv, const int* __restrict__ offs,
                         const int* __restrict__ cnt, const u16* __restrict__ srcs,
                         const float* __restrict__ bias, u16* __restrict__ Xout,
                         int do_relu, int wid, int lane, int* si, float* sw){
  int off = offs[wid], c = cnt[wid];
  float dvw = Dv[wid];
  float wself = __expf(fmaxf(Sv[wid] + dvw, 0.f));
  int cf = min(c, MAXD);
  float dl = 0.f;
  for (int j = lane; j < c; j += 64){
    int sidx = (int)srcs[off + j];
    float wgt = __expf(fmaxf(Sv[sidx] + dvw, 0.f));
    if (j < MAXD){ si[j] = sidx; sw[j] = wgt; }
    dl += wgt;
  }
  float inv = 1.f / (wave_sum(dl) + wself);
  for (int j = lane; j < cf; j += 64) sw[j] *= inv;
  int grp = lane >> 4, cg_ = lane & 15;
  const u32* H32 = (const u32*)H;
  union F8 { uint4 u; h2 p[4]; };
  h2 acc2[4] = {(h2){0,0},(h2){0,0},(h2){0,0},(h2){0,0}};
  if (grp == 0){
    F8 r; r.u = *(const uint4*)(H32 + (size_t)wid * 64 + cg_ * 4);
    f16 wh = (f16)(wself * inv); h2 w2 = {wh, wh};
    #pragma unroll
    for (int i = 0; i < 4; ++i) acc2[i] = r.p[i] * w2;
  }
  for (int base = 0; base < cf; base += 4){
    int j = base + grp;
    float wgt = 0.f; int sidx = 0;
    if (j < cf){ wgt = sw[j]; sidx = si[j]; }
    f16 wh = (f16)wgt; h2 w2 = {wh, wh};
    F8 r; r.u = *(const uint4*)(H32 + (size_t)sidx * 64 + cg_ * 4);
    #pragma unroll
    for (int i = 0; i < 4; ++i) acc2[i] += r.p[i] * w2;
  }
  for (int base = MAXD; base < c; base += 4){   // ultra-rare tail
    int j = base + grp;
    bool valid = j < c;
    int sidx = valid ? (int)srcs[off + j] : 0;
    float wgt = valid ? __expf(fmaxf(Sv[sidx] + dvw, 0.f)) * inv : 0.f;
    f16 wh = (f16)wgt; h2 w2 = {wh, wh};
    F8 r; r.u = *(const uint4*)(H32 + (size_t)sidx * 64 + cg_ * 4);
    #pragma unroll
    for (int i = 0; i < 4; ++i) acc2[i] += r.p[i] * w2;
  }
  union FU { h2 v; float f; };
  #pragma unroll
  for (int i = 0; i < 4; ++i){
    FU a; a.v = acc2[i];
    FU o1; o1.f = __shfl_xor(a.f, 16, 64); a.v = a.v + o1.v;
    FU o2; o2.f = __shfl_xor(a.f, 32, 64); a.v = a.v + o2.v;
    acc2[i] = a.v;
  }
  if (grp == 0){
    uint4 pk;
    u32* pkp = (u32*)&pk;
    #pragma unroll
    for (int qq = 0; qq < 4; ++qq){
      float o0 = (float)acc2[qq].x + bias[cg_ * 8 + 2 * qq];
      float o1 = (float)acc2[qq].y + bias[cg_ * 8 + 2 * qq + 1];
      if (do_relu){ o0 = fmaxf(o0, 0.f); o1 = fmaxf(o1, 0.f); }
      pkp[qq] = ((u32)f2h(o1) << 16) | (u32)f2h(o0);
    }
    *(uint4*)((u32*)Xout + (size_t)wid * 64 + cg_ * 4) = pk;
  }
}

// out-projection tile body (Wfo staged in Wl, 1024 uint4)
__device__ void out_body(const u16* __restrict__ X, const float* __restrict__ bias,
                         float* __restrict__ out, int blk, int tid, const uint4* Wl){
  int wv = tid >> 6, lane = tid & 63;
  int rtile = blk * 4 + wv;
  if (rtile >= NTILE) return;
  int q = lane >> 4, n = lane & 15;
  int arow = rtile * 16 + n;
  f32x4 acc[4];
  #pragma unroll
  for (int t = 0; t < 4; ++t) acc[t] = (f32x4){0.f, 0.f, 0.f, 0.f};
  union F8 { uint4 u; f16x8 v; };
  #pragma unroll
  for (int ks = 0; ks < 4; ++ks){
    F8 a; a.u = *(const uint4*)(X + (size_t)arow * DD + ks * 32 + q * 8);
    #pragma unroll
    for (int t = 0; t < 4; ++t){
      F8 b; b.u = Wl[(ks * 4 + t) * 64 + lane];
      acc[t] = __builtin_amdgcn_mfma_f32_16x16x32_f16(a.v, b.v, acc[t], 0, 0, 0);
    }
  }
  #pragma unroll
  for (int rg = 0; rg < 4; ++rg){
    int grow = rtile * 16 + q * 4 + rg;
    #pragma unroll
    for (int t = 0; t < 4; ++t)
      out[(size_t)grow * DYY + t * 16 + n] = acc[t][rg] + bias[t * 16 + n];
  }
}

__global__ __launch_bounds__(256, 4) void k_mega(GParams p){
  cg::grid_group grid = cg::this_grid();
  __shared__ __align__(16) char shraw[32768];   // reused per phase; grid.sync fences reuse
  int tid = threadIdx.x, bid = blockIdx.x, gsz = gridDim.x;
  int wv = tid >> 6, lane = tid & 63;

  // ---- P0: per-chunk dst histograms + weight fragments ----
  for (int u = bid; u < 216; u += gsz){
    if (u < GB){
      int* hist = (int*)shraw;
      hist[tid] = 0;
      __syncthreads();
      int e0 = u * EPB, e1 = min(e0 + EPB, EE);
      for (int e = e0 + tid; e < e1; e += 256) atomicAdd(&hist[p.dst[e] >> 8], 1);
      __syncthreads();
      p.hist2d[u * 256 + tid] = hist[tid];
    } else if (u < 204) wfrag_one(p.W1, p.Wf1, 8, (u - 196) * 256 + tid);
    else if (u < 212)   wfrag_one(p.W2, p.Wf2, 8, (u - 204) * 256 + tid);
    else                wfrag_one(p.Wo, p.Wfo, 4, (u - 212) * 256 + tid);
  }
  grid.sync();

  // ---- P1: per-bucket exclusive scan over chunks ----
  for (int b = bid; b < NB; b += gsz){
    int* sd = (int*)shraw;
    int v = (tid < GB) ? p.hist2d[tid * 256 + b] : 0;
    sd[tid] = v;
    __syncthreads();
    for (int o = 1; o < 256; o <<= 1){
      int t = (tid >= o) ? sd[tid - o] : 0;
      __syncthreads();
      sd[tid] += t;
      __syncthreads();
    }
    if (tid < GB) p.chunkbase[tid * 256 + b] = sd[tid] - v;
    if (tid == GB - 1) p.btot[b] = sd[tid];
  }
  grid.sync();

  // ---- P2: block 0 = bucket-base scan; blocks 1.. = layer-1 GEMM ----
  if (bid == 0){
    int* sd = (int*)shraw;
    int v = (tid < NB) ? p.btot[tid] : 0;
    sd[tid] = v;
    __syncthreads();
    for (int o = 1; o < 256; o <<= 1){
      int t = (tid >= o) ? sd[tid - o] : 0;
      __syncthreads();
      sd[tid] += t;
      __syncthreads();
    }
    if (tid < NB) p.bbase[tid] = sd[tid] - v;
  } else if (bid - 1 < GMM){
    uint4* Wl = (uint4*)shraw;
    stage_w(Wl, p.Wf1, 2048, tid);
    __syncthreads();
    for (int u = bid - 1; u < GMM; u += gsz - 1)
      gemm_body(p.X0, 1, p.Hbf, p.as1, p.ad1, p.Sv, p.Dv, u, tid, Wl);
  }
  grid.sync();

  // ---- P3: scatter into bucket-contiguous buf (no global atomics) ----
  for (int c = bid; c < GB; c += gsz){
    int* lcur = (int*)shraw;
    __syncthreads();
    lcur[tid] = (tid < NB) ? (p.chunkbase[c * 256 + tid] + p.bbase[tid]) : 0;
    __syncthreads();
    int e0 = c * EPB, e1 = min(e0 + EPB, EE);
    for (int e = e0 + tid; e < e1; e += 256){
      int d = p.dst[e];
      int pos = atomicAdd(&lcur[d >> 8], 1);
      p.buf[pos] = (u32)p.src[e] | ((u32)(d & 255) << 16);
    }
  }
  grid.sync();

  // ---- P4: per-bucket finalize -> offs/cnt/srcs ----
  for (int b = bid; b < NB; b += gsz){
    int* dh = (int*)shraw; int* sd = dh + 256; int* dcur = dh + 512;
    __syncthreads();
    int n = p.btot[b], base = p.bbase[b];
    dh[tid] = 0;
    __syncthreads();
    for (int i = tid; i < n; i += 256) atomicAdd(&dh[(p.buf[base + i] >> 16) & 255], 1);
    __syncthreads();
    int v = dh[tid];
    sd[tid] = v;
    __syncthreads();
    for (int o = 1; o < 256; o <<= 1){
      int t = (tid >= o) ? sd[tid - o] : 0;
      __syncthreads();
      sd[tid] += t;
      __syncthreads();
    }
    int excl = sd[tid] - v;
    dcur[tid] = base + excl;
    int d = (b << 8) + tid;
    if (d < NN){ p.offs[d] = base + excl; p.cnt[d] = v; }
    __syncthreads();
    for (int i = tid; i < n; i += 256){
      u32 uu = p.buf[base + i];
      int pos = atomicAdd(&dcur[(uu >> 16) & 255], 1);
      p.srcs[pos] = (u16)(uu & 0xffffu);
    }
  }
  grid.sync();

  // ---- P5: aggregation layer 1 (buf/Abf alias safe: P4 done with buf) ----
  {
    int* SI = (int*)shraw;
    float* SW = (float*)(shraw + 4 * MAXD * 4);
    for (int wid = bid * 4 + wv; wid < NN; wid += gsz * 4)
      agg_node(p.Hbf, p.Sv, p.Dv, p.offs, p.cnt, p.srcs, p.b1, p.Abf, 1,
               wid, lane, SI + wv * MAXD, SW + wv * MAXD);
  }
  grid.sync();

  // ---- P6: layer-2 GEMM ----
  if (bid < GMM){
    uint4* Wl = (uint4*)shraw;
    stage_w(Wl, p.Wf2, 2048, tid);
    __syncthreads();
    for (int u = bid; u < GMM; u += gsz)
      gemm_body(p.Abf, 0, p.Hbf, p.as2, p.ad2, p.Sv, p.Dv, u, tid, Wl);
  }
  grid.sync();

  // ---- P7: aggregation layer 2 ----
  {
    int* SI = (int*)shraw;
    float* SW = (float*)(shraw + 4 * MAXD * 4);
    for (int wid = bid * 4 + wv; wid < NN; wid += gsz * 4)
      agg_node(p.Hbf, p.Sv, p.Dv, p.offs, p.cnt, p.srcs, p.b2, p.Abf, 0,
               wid, lane, SI + wv * MAXD, SW + wv * MAXD);
  }
  grid.sync();

  // ---- P8: output projection ----
  if (bid < GMM){
    uint4* Wl = (uint4*)shraw;
    stage_w(Wl, p.Wfo, 1024, tid);
    __syncthreads();
    for (int u = bid; u < GMM; u += gsz)
      out_body(p.Abf, p.bo, p.out, u, tid, Wl);
  }
}

extern "C" void kernel_launch(void* const* d_in, const int* in_sizes, int n_in,
                              void* d_out, int out_size, void* d_ws, size_t ws_size,
                              hipStream_t stream) {
  const int* ei = (const int*)d_in[1];

  // workspace carve: ~33.5 MB. buf aliases Abf (dead until P5 writes Abf).
  char* w = (char*)d_ws;
  u16*   Hbf   = (u16*)w;   w += (size_t)NN * DD * 2;  // 12.8 MB (fp16)
  u16*   Abf   = (u16*)w;   w += (size_t)NN * DD * 2;  // 12.8 MB (fp16; buf alias)
  u32*   buf   = (u32*)Abf;
  float* Sv    = (float*)w; w += (size_t)NN * 4;
  float* Dv    = (float*)w; w += (size_t)NN * 4;
  int*   cnt   = (int*)w;   w += (size_t)NN * 4;
  int*   offs  = (int*)w;   w += (size_t)NN * 4;
  int*   btot  = (int*)w;   w += 1024;
  int*   bbase = (int*)w;   w += 1024;
  int*   hist2d    = (int*)w; w += GB * 256 * 4;
  int*   chunkbase = (int*)w; w += GB * 256 * 4;
  u16*   srcs  = (u16*)w;   w += (size_t)EE * 2;       // 3.2 MB
  u16*   Wf1   = (u16*)w;   w += 32768;
  u16*   Wf2   = (u16*)w;   w += 32768;
  u16*   Wfo   = (u16*)w;   w += 16384;

  GParams p;
  p.src = ei; p.dst = ei + EE;
  p.X0  = (const float*)d_in[0];
  p.W1  = (const float*)d_in[2];  p.as1 = (const float*)d_in[3];
  p.ad1 = (const float*)d_in[4];  p.b1  = (const float*)d_in[5];
  p.W2  = (const float*)d_in[6];  p.as2 = (const float*)d_in[7];
  p.ad2 = (const float*)d_in[8];  p.b2  = (const float*)d_in[9];
  p.Wo  = (const float*)d_in[10]; p.bo  = (const float*)d_in[11];
  p.out = (float*)d_out;
  p.Hbf = Hbf; p.Abf = Abf; p.srcs = srcs;
  p.Wf1 = Wf1; p.Wf2 = Wf2; p.Wfo = Wfo;
  p.buf = buf; p.Sv = Sv; p.Dv = Dv;
  p.cnt = cnt; p.offs = offs; p.btot = btot; p.bbase = bbase;
  p.hist2d = hist2d; p.chunkbase = chunkbase;

  // co-residency-guaranteed grid: blocks/CU from the occupancy API x 256 CUs
  int bpc = 0;
  if (hipOccupancyMaxActiveBlocksPerMultiprocessor(&bpc, (const void*)k_mega, 256, 0)
      != hipSuccess || bpc < 1) bpc = 4;
  int nblk = bpc * 256;
  if (nblk > 4096) nblk = 4096;
  void* args[] = { (void*)&p };
  hipLaunchCooperativeKernel((const void*)k_mega, dim3(nblk), dim3(256), args, 0, stream);
}

// Round 12
// 285.432 us; speedup vs baseline: 3.1621x; 3.1621x over previous
//
#include <hip/hip_runtime.h>
#include <hip/hip_fp16.h>

typedef unsigned short u16;
typedef unsigned int   u32;
typedef _Float16 f16;
typedef __attribute__((ext_vector_type(8))) f16 f16x8;
typedef __attribute__((ext_vector_type(2))) f16 h2;
typedef __attribute__((ext_vector_type(4))) float f32x4;

#define NN 50000
#define EE 1600000
#define DD 128
#define DYY 64
#define NB 196      // dst buckets: dst>>8
#define EPB 8192    // edges per bucketing chunk
#define GB 196      // ceil(EE/EPB)
#define MAXD 160    // per-wave LDS edge cache
#define NTILE 3125  // 50000/16 row tiles (exact)
#define GMM 782     // ceil(NTILE/4)

__device__ __forceinline__ u16 f2h(float f){
  union { f16 h; u16 u; } x; x.h = (f16)f; return x.u;
}
__device__ __forceinline__ float wave_sum(float v){
  #pragma unroll
  for (int s = 32; s; s >>= 1) v += __shfl_xor(v, s, 64);
  return v;
}

// fp32 W[K=128][N=nct*16] -> fp16 MFMA B-fragment layout:
// slot s=(ks*nct+t)*64+lane holds W[ks*32+(lane>>4)*8+j][t*16+(lane&15)], j=0..7
__device__ __forceinline__ void wfrag_one(const float* __restrict__ W, u16* __restrict__ Wf,
                                          int nct, int s){
  int lane = s & 63;
  int t  = (s >> 6) % nct;
  int ks = (s >> 6) / nct;
  int q = lane >> 4, n = lane & 15;
  int N = nct * 16;
  u16 tmp[8];
  #pragma unroll
  for (int j = 0; j < 8; ++j)
    tmp[j] = f2h(W[(ks * 32 + q * 8 + j) * N + t * 16 + n]);
  *(uint4*)(Wf + (size_t)s * 8) = *(const uint4*)tmp;
}

// launch A: blocks 0..195 per-chunk dst-bucket histograms; 196..203 W1 frags;
// 204..211 W2; 212..215 Wout.
__global__ __launch_bounds__(256) void kA_prep(const int* __restrict__ dst, int* __restrict__ hist2d,
                                               const float* __restrict__ W1, const float* __restrict__ W2,
                                               const float* __restrict__ Wo,
                                               u16* __restrict__ Wf1, u16* __restrict__ Wf2,
                                               u16* __restrict__ Wfo){
  int b = blockIdx.x, tid = threadIdx.x;
  if (b < GB){
    __shared__ int hist[256];
    hist[tid] = 0;
    __syncthreads();
    int e0 = b * EPB, e1 = min(e0 + EPB, EE);
    for (int e = e0 + tid; e < e1; e += 256) atomicAdd(&hist[dst[e] >> 8], 1);
    __syncthreads();
    hist2d[b * 256 + tid] = hist[tid];
  } else if (b < 204) wfrag_one(W1, Wf1, 8, (b - 196) * 256 + tid);
  else if (b < 212)   wfrag_one(W2, Wf2, 8, (b - 204) * 256 + tid);
  else                wfrag_one(Wo, Wfo, 4, (b - 212) * 256 + tid);
}

// MFMA GEMM tile: stages W fragments into Wl then computes 4 row-tiles (one/wave),
// A-fragments straight from global (xf32: fp32->fp16 convert). Fused Sv/Dv epilogue.
__device__ __forceinline__ void gemm_tile(const void* __restrict__ X, int xf32,
                                          const u16* __restrict__ Wf, u16* __restrict__ Hout,
                                          const float* __restrict__ as, const float* __restrict__ ad,
                                          float* __restrict__ Sv, float* __restrict__ Dv,
                                          int blk, int tid, uint4* Wl){
  const uint4* Wg = (const uint4*)Wf;
  #pragma unroll
  for (int i = 0; i < 8; ++i) Wl[tid + 256 * i] = Wg[tid + 256 * i];
  __syncthreads();
  int wv = tid >> 6, lane = tid & 63;
  int rtile = blk * 4 + wv;
  if (rtile >= NTILE) return;          // no barriers after this point
  int q = lane >> 4, n = lane & 15;
  int arow = rtile * 16 + n;
  f32x4 acc[8];
  #pragma unroll
  for (int t = 0; t < 8; ++t) acc[t] = (f32x4){0.f, 0.f, 0.f, 0.f};
  union F8 { uint4 u; f16x8 v; f16 h[8]; };
  #pragma unroll
  for (int ks = 0; ks < 4; ++ks){
    int kb = ks * 32 + q * 8;
    F8 a;
    if (!xf32){
      a.u = *(const uint4*)((const u16*)X + (size_t)arow * DD + kb);
    } else {
      const float* xp = (const float*)X + (size_t)arow * DD + kb;
      float4 f0 = *(const float4*)xp;
      float4 f1 = *(const float4*)(xp + 4);
      a.h[0] = (f16)f0.x; a.h[1] = (f16)f0.y; a.h[2] = (f16)f0.z; a.h[3] = (f16)f0.w;
      a.h[4] = (f16)f1.x; a.h[5] = (f16)f1.y; a.h[6] = (f16)f1.z; a.h[7] = (f16)f1.w;
    }
    #pragma unroll
    for (int t = 0; t < 8; ++t){
      F8 b; b.u = Wl[(ks * 8 + t) * 64 + lane];
      acc[t] = __builtin_amdgcn_mfma_f32_16x16x32_f16(a.v, b.v, acc[t], 0, 0, 0);
    }
  }
  float ps[4] = {0, 0, 0, 0}, pd[4] = {0, 0, 0, 0};
  #pragma unroll
  for (int t = 0; t < 8; ++t){
    float a_s = as[t * 16 + n];
    float a_d = ad[t * 16 + n];
    #pragma unroll
    for (int rg = 0; rg < 4; ++rg){
      ps[rg] += acc[t][rg] * a_s;
      pd[rg] += acc[t][rg] * a_d;
    }
  }
  #pragma unroll
  for (int rg = 0; rg < 4; ++rg){
    #pragma unroll
    for (int s = 1; s < 16; s <<= 1){
      ps[rg] += __shfl_xor(ps[rg], s, 64);
      pd[rg] += __shfl_xor(pd[rg], s, 64);
    }
  }
  #pragma unroll
  for (int rg = 0; rg < 4; ++rg){
    int grow = rtile * 16 + q * 4 + rg;
    if (n == 0){ Sv[grow] = ps[rg]; Dv[grow] = pd[rg]; }
    #pragma unroll
    for (int t = 0; t < 8; ++t)
      Hout[(size_t)grow * DD + t * 16 + n] = f2h(acc[t][rg]);
  }
}

// launch BC (fused; both halves depend only on kA):
//   blocks 0..195: per-chunk bucket scan (redundant coalesced column sums of hist2d)
//                  + scatter chunk into bucket-contiguous buf (no global atomics)
//   blocks 196..977: layer-1 GEMM tiles (fp32 X input)
__global__ __launch_bounds__(256) void kBC(const int* __restrict__ src, const int* __restrict__ dst,
                                           const int* __restrict__ hist2d,
                                           int* __restrict__ btot, int* __restrict__ bbase,
                                           u32* __restrict__ buf,
                                           const float* __restrict__ X0, const u16* __restrict__ Wf1,
                                           u16* __restrict__ Hbf,
                                           const float* __restrict__ as1, const float* __restrict__ ad1,
                                           float* __restrict__ Sv, float* __restrict__ Dv){
  __shared__ __align__(16) uint4 Wl[2048];   // gemm blocks: W tile; scatter blocks: 2KB scratch
  int b = blockIdx.x, tid = threadIdx.x;
  if (b < GB){
    int* lcur = (int*)Wl;          // 256 ints
    int* sd   = ((int*)Wl) + 256;  // 256 ints
    int c = b;                     // this block's chunk
    int pre = 0, tot = 0;          // tid = bucket index
    for (int cc = 0; cc < GB; ++cc){
      int v = hist2d[cc * 256 + tid];   // coalesced across tid
      if (cc < c) pre += v;
      tot += v;
    }
    sd[tid] = tot;
    __syncthreads();
    for (int o = 1; o < 256; o <<= 1){
      int t = (tid >= o) ? sd[tid - o] : 0;
      __syncthreads();
      sd[tid] += t;
      __syncthreads();
    }
    int bb = sd[tid] - tot;        // global bucket base
    if (c == 0){ btot[tid] = tot; bbase[tid] = bb; }   // for kD
    lcur[tid] = bb + pre;
    __syncthreads();
    int e0 = c * EPB, e1 = min(e0 + EPB, EE);
    for (int e = e0 + tid; e < e1; e += 256){
      int d = dst[e];
      int pos = atomicAdd(&lcur[d >> 8], 1);
      buf[pos] = (u32)src[e] | ((u32)(d & 255) << 16);
    }
  } else {
    gemm_tile(X0, 1, Wf1, Hbf, as1, ad1, Sv, Dv, b - GB, tid, Wl);
  }
}

// launch D: per-bucket finalize -> offs/cnt/srcs (bucket region is L2-resident)
__global__ __launch_bounds__(256) void kD_finalize(const u32* __restrict__ buf,
                                                   const int* __restrict__ btot, const int* __restrict__ bbase,
                                                   int* __restrict__ offs, int* __restrict__ cnt,
                                                   u16* __restrict__ srcs){
  __shared__ int dh[256];
  __shared__ int sd[256];
  __shared__ int dcur[256];
  int tid = threadIdx.x, b = blockIdx.x;
  int n = btot[b], base = bbase[b];
  dh[tid] = 0;
  __syncthreads();
  for (int i = tid; i < n; i += 256) atomicAdd(&dh[(buf[base + i] >> 16) & 255], 1);
  __syncthreads();
  int v = dh[tid];
  sd[tid] = v;
  __syncthreads();
  for (int o = 1; o < 256; o <<= 1){
    int t = (tid >= o) ? sd[tid - o] : 0;
    __syncthreads();
    sd[tid] += t;
    __syncthreads();
  }
  int excl = sd[tid] - v;
  dcur[tid] = base + excl;
  int d = (b << 8) + tid;
  if (d < NN){ offs[d] = base + excl; cnt[d] = v; }
  __syncthreads();
  for (int i = tid; i < n; i += 256){
    u32 u = buf[base + i];
    int pos = atomicAdd(&dcur[(u >> 16) & 255], 1);
    srcs[pos] = (u16)(u & 0xffffu);
  }
}

// one wave per destination. No-max softmax (logits = relu(.) small, exp fp32-safe);
// weights normalized in LDS (sum=1) so fp16 accumulation is bounded. Phase B is the
// proven 4-edge loop (16 VGPR, ~73% occupancy, fabric-bound ~58us).
__global__ __launch_bounds__(256) void k_agg(const u16* __restrict__ H,
                                             const float* __restrict__ Sv, const float* __restrict__ Dv,
                                             const int* __restrict__ offs, const int* __restrict__ cnt,
                                             const u16* __restrict__ srcs,
                                             const float* __restrict__ bias,
                                             u16* __restrict__ Xout, int do_relu){
  __shared__ int   s_i[4][MAXD];
  __shared__ float s_w[4][MAXD];
  int gid = blockIdx.x * blockDim.x + threadIdx.x;
  int wid = gid >> 6, lane = gid & 63;
  int wv = threadIdx.x >> 6;
  if (wid >= NN) return;
  int off = offs[wid], c = cnt[wid];
  float dvw = Dv[wid];
  float wself = __expf(fmaxf(Sv[wid] + dvw, 0.f));
  int cf = min(c, MAXD);
  float dl = 0.f;
  for (int j = lane; j < c; j += 64){
    int sidx = (int)srcs[off + j];
    float wgt = __expf(fmaxf(Sv[sidx] + dvw, 0.f));
    if (j < MAXD){ s_i[wv][j] = sidx; s_w[wv][j] = wgt; }
    dl += wgt;
  }
  float inv = 1.f / (wave_sum(dl) + wself);
  for (int j = lane; j < cf; j += 64) s_w[wv][j] *= inv;
  int grp = lane >> 4, cg = lane & 15;
  const u32* H32 = (const u32*)H;
  union F8 { uint4 u; h2 p[4]; };
  h2 acc2[4] = {(h2){0,0},(h2){0,0},(h2){0,0},(h2){0,0}};
  if (grp == 0){
    F8 r; r.u = *(const uint4*)(H32 + (size_t)wid * 64 + cg * 4);
    f16 wh = (f16)(wself * inv); h2 w2 = {wh, wh};
    #pragma unroll
    for (int i = 0; i < 4; ++i) acc2[i] = r.p[i] * w2;
  }
  for (int base = 0; base < cf; base += 4){
    int j = base + grp;
    float wgt = 0.f; int sidx = 0;
    if (j < cf){ wgt = s_w[wv][j]; sidx = s_i[wv][j]; }
    f16 wh = (f16)wgt; h2 w2 = {wh, wh};
    F8 r; r.u = *(const uint4*)(H32 + (size_t)sidx * 64 + cg * 4);
    #pragma unroll
    for (int i = 0; i < 4; ++i) acc2[i] += r.p[i] * w2;
  }
  for (int base = MAXD; base < c; base += 4){   // ultra-rare tail
    int j = base + grp;
    bool valid = j < c;
    int sidx = valid ? (int)srcs[off + j] : 0;
    float wgt = valid ? __expf(fmaxf(Sv[sidx] + dvw, 0.f)) * inv : 0.f;
    f16 wh = (f16)wgt; h2 w2 = {wh, wh};
    F8 r; r.u = *(const uint4*)(H32 + (size_t)sidx * 64 + cg * 4);
    #pragma unroll
    for (int i = 0; i < 4; ++i) acc2[i] += r.p[i] * w2;
  }
  union FU { h2 v; float f; };
  #pragma unroll
  for (int i = 0; i < 4; ++i){
    FU a; a.v = acc2[i];
    FU o1; o1.f = __shfl_xor(a.f, 16, 64); a.v = a.v + o1.v;
    FU o2; o2.f = __shfl_xor(a.f, 32, 64); a.v = a.v + o2.v;
    acc2[i] = a.v;
  }
  if (grp == 0){
    uint4 pk;
    u32* pkp = (u32*)&pk;
    #pragma unroll
    for (int qq = 0; qq < 4; ++qq){
      float o0 = (float)acc2[qq].x + bias[cg * 8 + 2 * qq];
      float o1 = (float)acc2[qq].y + bias[cg * 8 + 2 * qq + 1];
      if (do_relu){ o0 = fmaxf(o0, 0.f); o1 = fmaxf(o1, 0.f); }
      pkp[qq] = ((u32)f2h(o1) << 16) | (u32)f2h(o0);
    }
    *(uint4*)((u32*)Xout + (size_t)wid * 64 + cg * 4) = pk;
  }
}

// layer-2 GEMM (fp16 X)
__global__ __launch_bounds__(256) void k_gemm2(const u16* __restrict__ X, const u16* __restrict__ Wf,
                                               u16* __restrict__ Hout,
                                               const float* __restrict__ as, const float* __restrict__ ad,
                                               float* __restrict__ Sv, float* __restrict__ Dv){
  __shared__ __align__(16) uint4 Wl[2048];
  gemm_tile(X, 0, Wf, Hout, as, ad, Sv, Dv, blockIdx.x, threadIdx.x, Wl);
}

// out = X·Wout + b via MFMA; fp32 stores
__global__ __launch_bounds__(256) void k_out(const u16* __restrict__ X,
                                             const u16* __restrict__ Wfo,
                                             const float* __restrict__ bias,
                                             float* __restrict__ out){
  __shared__ __align__(16) uint4 Wl[1024];
  int tid = threadIdx.x;
  const uint4* Wg = (const uint4*)Wfo;
  #pragma unroll
  for (int i = 0; i < 4; ++i) Wl[tid + 256 * i] = Wg[tid + 256 * i];
  __syncthreads();
  int wv = tid >> 6, lane = tid & 63;
  int rtile = blockIdx.x * 4 + wv;
  if (rtile >= NTILE) return;
  int q = lane >> 4, n = lane & 15;
  int arow = rtile * 16 + n;
  f32x4 acc[4];
  #pragma unroll
  for (int t = 0; t < 4; ++t) acc[t] = (f32x4){0.f, 0.f, 0.f, 0.f};
  union F8 { uint4 u; f16x8 v; };
  #pragma unroll
  for (int ks = 0; ks < 4; ++ks){
    F8 a; a.u = *(const uint4*)(X + (size_t)arow * DD + ks * 32 + q * 8);
    #pragma unroll
    for (int t = 0; t < 4; ++t){
      F8 b; b.u = Wl[(ks * 4 + t) * 64 + lane];
      acc[t] = __builtin_amdgcn_mfma_f32_16x16x32_f16(a.v, b.v, acc[t], 0, 0, 0);
    }
  }
  float bo[4];
  #pragma unroll
  for (int t = 0; t < 4; ++t) bo[t] = bias[t * 16 + n];
  #pragma unroll
  for (int rg = 0; rg < 4; ++rg){
    int grow = rtile * 16 + q * 4 + rg;
    #pragma unroll
    for (int t = 0; t < 4; ++t)
      out[(size_t)grow * DYY + t * 16 + n] = acc[t][rg] + bo[t];
  }
}

extern "C" void kernel_launch(void* const* d_in, const int* in_sizes, int n_in,
                              void* d_out, int out_size, void* d_ws, size_t ws_size,
                              hipStream_t stream) {
  const float* node_x = (const float*)d_in[0];
  const int* ei   = (const int*)d_in[1];
  const int* srcp = ei;
  const int* dstp = ei + EE;
  const float* W1  = (const float*)d_in[2];
  const float* as1 = (const float*)d_in[3];
  const float* ad1 = (const float*)d_in[4];
  const float* b1  = (const float*)d_in[5];
  const float* W2  = (const float*)d_in[6];
  const float* as2 = (const float*)d_in[7];
  const float* ad2 = (const float*)d_in[8];
  const float* b2  = (const float*)d_in[9];
  const float* Wo  = (const float*)d_in[10];
  const float* bo  = (const float*)d_in[11];

  // workspace carve: ~33.5 MB. buf aliases Abf (dead until first k_agg write).
  char* w = (char*)d_ws;
  u16*   Hbf   = (u16*)w;   w += (size_t)NN * DD * 2;  // 12.8 MB (fp16)
  u16*   Abf   = (u16*)w;   w += (size_t)NN * DD * 2;  // 12.8 MB (fp16; buf alias)
  u32*   buf   = (u32*)Abf;
  float* Sv    = (float*)w; w += (size_t)NN * 4;
  float* Dv    = (float*)w; w += (size_t)NN * 4;
  int*   cnt   = (int*)w;   w += (size_t)NN * 4;
  int*   offs  = (int*)w;   w += (size_t)NN * 4;
  int*   btot  = (int*)w;   w += 1024;
  int*   bbase = (int*)w;   w += 1024;
  int*   hist2d = (int*)w;  w += GB * 256 * 4;          // 200 KB
  u16*   srcs  = (u16*)w;   w += (size_t)EE * 2;        // 3.2 MB
  u16*   Wf1   = (u16*)w;   w += 32768;
  u16*   Wf2   = (u16*)w;   w += 32768;
  u16*   Wfo   = (u16*)w;   w += 16384;

  const int TB = 256;
  const int gWav = (NN * 64) / TB;       // 12500 (one wave per node)

  kA_prep    <<<216,      TB, 0, stream>>>(dstp, hist2d, W1, W2, Wo, Wf1, Wf2, Wfo);
  kBC        <<<GB + GMM, TB, 0, stream>>>(srcp, dstp, hist2d, btot, bbase, buf,
                                           node_x, Wf1, Hbf, as1, ad1, Sv, Dv);
  kD_finalize<<<NB,       TB, 0, stream>>>(buf, btot, bbase, offs, cnt, srcs);

  k_agg  <<<gWav, TB, 0, stream>>>(Hbf, Sv, Dv, offs, cnt, srcs, b1, Abf, 1);
  k_gemm2<<<GMM,  TB, 0, stream>>>(Abf, Wf2, Hbf, as2, ad2, Sv, Dv);
  k_agg  <<<gWav, TB, 0, stream>>>(Hbf, Sv, Dv, offs, cnt, srcs, b2, Abf, 0);
  k_out  <<<GMM,  TB, 0, stream>>>(Abf, Wfo, bo, (float*)d_out);
}

// Round 13
// 283.388 us; speedup vs baseline: 3.1849x; 1.0072x over previous
//
#include <hip/hip_runtime.h>
#include <hip/hip_fp16.h>

typedef unsigned short u16;
typedef unsigned int   u32;
typedef _Float16 f16;
typedef __attribute__((ext_vector_type(8))) f16 f16x8;
typedef __attribute__((ext_vector_type(2))) f16 h2;
typedef __attribute__((ext_vector_type(4))) float f32x4;

#define NN 50000
#define EE 1600000
#define DD 128
#define DYY 64
#define NB 196      // dst buckets: dst>>8
#define EPB 8192    // edges per bucketing chunk
#define GB 196      // ceil(EE/EPB)
#define MAXD 160    // per-wave LDS edge cache
#define NTILE 3125  // 50000/16 row tiles (exact)
#define GMM 782     // ceil(NTILE/4)
#define XST 144     // LDS x-tile row stride in u16 (288 B: 16B-aligned, ~4-way max)

__device__ __forceinline__ u16 f2h(float f){
  union { f16 h; u16 u; } x; x.h = (f16)f; return x.u;
}
__device__ __forceinline__ float wave_sum(float v){
  #pragma unroll
  for (int s = 32; s; s >>= 1) v += __shfl_xor(v, s, 64);
  return v;
}

// fp32 W[K=128][N=nct*16] -> fp16 MFMA B-fragment layout:
// slot s=(ks*nct+t)*64+lane holds W[ks*32+(lane>>4)*8+j][t*16+(lane&15)], j=0..7
__device__ __forceinline__ void wfrag_one(const float* __restrict__ W, u16* __restrict__ Wf,
                                          int nct, int s){
  int lane = s & 63;
  int t  = (s >> 6) % nct;
  int ks = (s >> 6) / nct;
  int q = lane >> 4, n = lane & 15;
  int N = nct * 16;
  u16 tmp[8];
  #pragma unroll
  for (int j = 0; j < 8; ++j)
    tmp[j] = f2h(W[(ks * 32 + q * 8 + j) * N + t * 16 + n]);
  *(uint4*)(Wf + (size_t)s * 8) = *(const uint4*)tmp;
}

// launch A: blocks 0..195 per-chunk dst-bucket histograms; 196..203 W1 frags;
// 204..211 W2; 212..215 Wout.
__global__ __launch_bounds__(256) void kA_prep(const int* __restrict__ dst, int* __restrict__ hist2d,
                                               const float* __restrict__ W1, const float* __restrict__ W2,
                                               const float* __restrict__ Wo,
                                               u16* __restrict__ Wf1, u16* __restrict__ Wf2,
                                               u16* __restrict__ Wfo){
  int b = blockIdx.x, tid = threadIdx.x;
  if (b < GB){
    __shared__ int hist[256];
    hist[tid] = 0;
    __syncthreads();
    int e0 = b * EPB, e1 = min(e0 + EPB, EE);
    for (int e = e0 + tid; e < e1; e += 256) atomicAdd(&hist[dst[e] >> 8], 1);
    __syncthreads();
    hist2d[b * 256 + tid] = hist[tid];
  } else if (b < 204) wfrag_one(W1, Wf1, 8, (b - 196) * 256 + tid);
  else if (b < 212)   wfrag_one(W2, Wf2, 8, (b - 204) * 256 + tid);
  else                wfrag_one(Wo, Wfo, 4, (b - 212) * 256 + tid);
}

// full-tile-per-wave MFMA GEMM (layer 1, fp32 X): stages W frags into Wl,
// 4 row-tiles/block (one per wave), fused Sv/Dv epilogue.
__device__ __forceinline__ void gemm_tile(const float* __restrict__ X,
                                          const u16* __restrict__ Wf, u16* __restrict__ Hout,
                                          const float* __restrict__ as, const float* __restrict__ ad,
                                          float* __restrict__ Sv, float* __restrict__ Dv,
                                          int blk, int tid, uint4* Wl){
  const uint4* Wg = (const uint4*)Wf;
  #pragma unroll
  for (int i = 0; i < 8; ++i) Wl[tid + 256 * i] = Wg[tid + 256 * i];
  __syncthreads();
  int wv = tid >> 6, lane = tid & 63;
  int rtile = blk * 4 + wv;
  if (rtile >= NTILE) return;
  int q = lane >> 4, n = lane & 15;
  int arow = rtile * 16 + n;
  f32x4 acc[8];
  #pragma unroll
  for (int t = 0; t < 8; ++t) acc[t] = (f32x4){0.f, 0.f, 0.f, 0.f};
  union F8 { uint4 u; f16x8 v; f16 h[8]; };
  #pragma unroll
  for (int ks = 0; ks < 4; ++ks){
    int kb = ks * 32 + q * 8;
    const float* xp = X + (size_t)arow * DD + kb;
    float4 f0 = *(const float4*)xp;
    float4 f1 = *(const float4*)(xp + 4);
    F8 a;
    a.h[0] = (f16)f0.x; a.h[1] = (f16)f0.y; a.h[2] = (f16)f0.z; a.h[3] = (f16)f0.w;
    a.h[4] = (f16)f1.x; a.h[5] = (f16)f1.y; a.h[6] = (f16)f1.z; a.h[7] = (f16)f1.w;
    #pragma unroll
    for (int t = 0; t < 8; ++t){
      F8 b; b.u = Wl[(ks * 8 + t) * 64 + lane];
      acc[t] = __builtin_amdgcn_mfma_f32_16x16x32_f16(a.v, b.v, acc[t], 0, 0, 0);
    }
  }
  float ps[4] = {0, 0, 0, 0}, pd[4] = {0, 0, 0, 0};
  #pragma unroll
  for (int t = 0; t < 8; ++t){
    float a_s = as[t * 16 + n];
    float a_d = ad[t * 16 + n];
    #pragma unroll
    for (int rg = 0; rg < 4; ++rg){
      ps[rg] += acc[t][rg] * a_s;
      pd[rg] += acc[t][rg] * a_d;
    }
  }
  #pragma unroll
  for (int rg = 0; rg < 4; ++rg){
    #pragma unroll
    for (int s = 1; s < 16; s <<= 1){
      ps[rg] += __shfl_xor(ps[rg], s, 64);
      pd[rg] += __shfl_xor(pd[rg], s, 64);
    }
  }
  #pragma unroll
  for (int rg = 0; rg < 4; ++rg){
    int grow = rtile * 16 + q * 4 + rg;
    if (n == 0){ Sv[grow] = ps[rg]; Dv[grow] = pd[rg]; }
    #pragma unroll
    for (int t = 0; t < 8; ++t)
      Hout[(size_t)grow * DD + t * 16 + n] = f2h(acc[t][rg]);
  }
}

// launch BC (fused; both halves depend only on kA):
//   blocks 0..195: per-chunk bucket scan + scatter into bucket-contiguous buf
//   blocks 196..977: layer-1 GEMM tiles (fp32 X) -> Hbf1, Sv1, Dv1
__global__ __launch_bounds__(256) void kBC(const int* __restrict__ src, const int* __restrict__ dst,
                                           const int* __restrict__ hist2d,
                                           int* __restrict__ btot, int* __restrict__ bbase,
                                           u32* __restrict__ buf,
                                           const float* __restrict__ X0, const u16* __restrict__ Wf1,
                                           u16* __restrict__ Hbf1,
                                           const float* __restrict__ as1, const float* __restrict__ ad1,
                                           float* __restrict__ Sv1, float* __restrict__ Dv1){
  __shared__ __align__(16) uint4 Wl[2048];
  int b = blockIdx.x, tid = threadIdx.x;
  if (b < GB){
    int* lcur = (int*)Wl;
    int* sd   = ((int*)Wl) + 256;
    int c = b;
    int pre = 0, tot = 0;
    for (int cc = 0; cc < GB; ++cc){
      int v = hist2d[cc * 256 + tid];
      if (cc < c) pre += v;
      tot += v;
    }
    sd[tid] = tot;
    __syncthreads();
    for (int o = 1; o < 256; o <<= 1){
      int t = (tid >= o) ? sd[tid - o] : 0;
      __syncthreads();
      sd[tid] += t;
      __syncthreads();
    }
    int bb = sd[tid] - tot;
    if (c == 0){ btot[tid] = tot; bbase[tid] = bb; }
    lcur[tid] = bb + pre;
    __syncthreads();
    int e0 = c * EPB, e1 = min(e0 + EPB, EE);
    for (int e = e0 + tid; e < e1; e += 256){
      int d = dst[e];
      int pos = atomicAdd(&lcur[d >> 8], 1);
      buf[pos] = (u32)src[e] | ((u32)(d & 255) << 16);
    }
  } else {
    gemm_tile(X0, Wf1, Hbf1, as1, ad1, Sv1, Dv1, b - GB, tid, Wl);
  }
}

// launch D: per-bucket finalize -> offs/cnt/srcs
__global__ __launch_bounds__(256) void kD_finalize(const u32* __restrict__ buf,
                                                   const int* __restrict__ btot, const int* __restrict__ bbase,
                                                   int* __restrict__ offs, int* __restrict__ cnt,
                                                   u16* __restrict__ srcs){
  __shared__ int dh[256];
  __shared__ int sd[256];
  __shared__ int dcur[256];
  int tid = threadIdx.x, b = blockIdx.x;
  int n = btot[b], base = bbase[b];
  dh[tid] = 0;
  __syncthreads();
  for (int i = tid; i < n; i += 256) atomicAdd(&dh[(buf[base + i] >> 16) & 255], 1);
  __syncthreads();
  int v = dh[tid];
  sd[tid] = v;
  __syncthreads();
  for (int o = 1; o < 256; o <<= 1){
    int t = (tid >= o) ? sd[tid - o] : 0;
    __syncthreads();
    sd[tid] += t;
    __syncthreads();
  }
  int excl = sd[tid] - v;
  dcur[tid] = base + excl;
  int d = (b << 8) + tid;
  if (d < NN){ offs[d] = base + excl; cnt[d] = v; }
  __syncthreads();
  for (int i = tid; i < n; i += 256){
    u32 u = buf[base + i];
    int pos = atomicAdd(&dcur[(u >> 16) & 255], 1);
    srcs[pos] = (u16)(u & 0xffffu);
  }
}

// per-node aggregation writing the result row to LDS (proven r10/r12 body; only the
// final store target changed). si/sw are this wave's private LDS slices.
__device__ void agg_node_lds(const u16* __restrict__ H, const float* __restrict__ Sv,
                             const float* __restrict__ Dv, const int* __restrict__ offs,
                             const int* __restrict__ cnt, const u16* __restrict__ srcs,
                             const float* __restrict__ bias, u16* __restrict__ xrow,
                             int do_relu, int wid, int lane, int* si, float* sw){
  int off = offs[wid], c = cnt[wid];
  float dvw = Dv[wid];
  float wself = __expf(fmaxf(Sv[wid] + dvw, 0.f));
  int cf = min(c, MAXD);
  float dl = 0.f;
  for (int j = lane; j < c; j += 64){
    int sidx = (int)srcs[off + j];
    float wgt = __expf(fmaxf(Sv[sidx] + dvw, 0.f));
    if (j < MAXD){ si[j] = sidx; sw[j] = wgt; }
    dl += wgt;
  }
  float inv = 1.f / (wave_sum(dl) + wself);
  for (int j = lane; j < cf; j += 64) sw[j] *= inv;
  int grp = lane >> 4, cg_ = lane & 15;
  const u32* H32 = (const u32*)H;
  union F8 { uint4 u; h2 p[4]; };
  h2 acc2[4] = {(h2){0,0},(h2){0,0},(h2){0,0},(h2){0,0}};
  if (grp == 0){
    F8 r; r.u = *(const uint4*)(H32 + (size_t)wid * 64 + cg_ * 4);
    f16 wh = (f16)(wself * inv); h2 w2 = {wh, wh};
    #pragma unroll
    for (int i = 0; i < 4; ++i) acc2[i] = r.p[i] * w2;
  }
  for (int base = 0; base < cf; base += 4){
    int j = base + grp;
    float wgt = 0.f; int sidx = 0;
    if (j < cf){ wgt = sw[j]; sidx = si[j]; }
    f16 wh = (f16)wgt; h2 w2 = {wh, wh};
    F8 r; r.u = *(const uint4*)(H32 + (size_t)sidx * 64 + cg_ * 4);
    #pragma unroll
    for (int i = 0; i < 4; ++i) acc2[i] += r.p[i] * w2;
  }
  for (int base = MAXD; base < c; base += 4){   // ultra-rare tail
    int j = base + grp;
    bool valid = j < c;
    int sidx = valid ? (int)srcs[off + j] : 0;
    float wgt = valid ? __expf(fmaxf(Sv[sidx] + dvw, 0.f)) * inv : 0.f;
    f16 wh = (f16)wgt; h2 w2 = {wh, wh};
    F8 r; r.u = *(const uint4*)(H32 + (size_t)sidx * 64 + cg_ * 4);
    #pragma unroll
    for (int i = 0; i < 4; ++i) acc2[i] += r.p[i] * w2;
  }
  union FU { h2 v; float f; };
  #pragma unroll
  for (int i = 0; i < 4; ++i){
    FU a; a.v = acc2[i];
    FU o1; o1.f = __shfl_xor(a.f, 16, 64); a.v = a.v + o1.v;
    FU o2; o2.f = __shfl_xor(a.f, 32, 64); a.v = a.v + o2.v;
    acc2[i] = a.v;
  }
  if (grp == 0){
    uint4 pk;
    u32* pkp = (u32*)&pk;
    #pragma unroll
    for (int qq = 0; qq < 4; ++qq){
      float o0 = (float)acc2[qq].x + bias[cg_ * 8 + 2 * qq];
      float o1 = (float)acc2[qq].y + bias[cg_ * 8 + 2 * qq + 1];
      if (do_relu){ o0 = fmaxf(o0, 0.f); o1 = fmaxf(o1, 0.f); }
      pkp[qq] = ((u32)f2h(o1) << 16) | (u32)f2h(o0);
    }
    *(uint4*)(xrow + cg_ * 8) = pk;   // LDS row store (2-way banks: free)
  }
}

// kE: fused agg-layer1 (x1 rows -> LDS) + layer-2 GEMM tile.
// Block owns rtile = blockIdx.x (16 nodes). Wave wv aggregates nodes wv*4..wv*4+3,
// then waves jointly compute the GEMM tile (wave wv -> cols t=2wv,2wv+1),
// Sv2/Dv2 finished via 16-float LDS reduction. Writes Hbf2/Sv2/Dv2 (NOT the
// layer-1 buffers — other blocks still read those).
__global__ __launch_bounds__(256) void kE(const u16* __restrict__ Hbf1,
                                          const float* __restrict__ Sv1, const float* __restrict__ Dv1,
                                          const int* __restrict__ offs, const int* __restrict__ cnt,
                                          const u16* __restrict__ srcs, const float* __restrict__ b1,
                                          const u16* __restrict__ Wf2,
                                          const float* __restrict__ as2, const float* __restrict__ ad2,
                                          u16* __restrict__ Hbf2,
                                          float* __restrict__ Sv2, float* __restrict__ Dv2){
  __shared__ __align__(16) u16 Xs[16 * XST];
  __shared__ int   s_i[4][MAXD];
  __shared__ float s_w[4][MAXD];
  __shared__ float svp[16], dvp[16];
  int tid = threadIdx.x, wv = tid >> 6, lane = tid & 63;
  int rtile = blockIdx.x;
  if (tid < 16){ svp[tid] = 0.f; dvp[tid] = 0.f; }
  #pragma unroll
  for (int k = 0; k < 4; ++k){
    int r = wv * 4 + k;
    agg_node_lds(Hbf1, Sv1, Dv1, offs, cnt, srcs, b1, Xs + r * XST, 1,
                 rtile * 16 + r, lane, s_i[wv], s_w[wv]);
  }
  __syncthreads();
  // GEMM: b-frags for t = 2wv, 2wv+1 from global Wf2 (32 KB, L2-resident broadcast)
  const uint4* Wg = (const uint4*)Wf2;
  int q = lane >> 4, n = lane & 15;
  f32x4 acc[2] = {(f32x4){0.f,0.f,0.f,0.f}, (f32x4){0.f,0.f,0.f,0.f}};
  union F8 { uint4 u; f16x8 v; };
  #pragma unroll
  for (int ks = 0; ks < 4; ++ks){
    F8 a; a.u = *(const uint4*)((const char*)Xs + n * (XST * 2) + ks * 64 + q * 16);
    #pragma unroll
    for (int tt = 0; tt < 2; ++tt){
      F8 b; b.u = Wg[(ks * 8 + wv * 2 + tt) * 64 + lane];
      acc[tt] = __builtin_amdgcn_mfma_f32_16x16x32_f16(a.v, b.v, acc[tt], 0, 0, 0);
    }
  }
  float ps[4] = {0, 0, 0, 0}, pd[4] = {0, 0, 0, 0};
  #pragma unroll
  for (int tt = 0; tt < 2; ++tt){
    int t = wv * 2 + tt;
    float a_s = as2[t * 16 + n];
    float a_d = ad2[t * 16 + n];
    #pragma unroll
    for (int rg = 0; rg < 4; ++rg){
      ps[rg] += acc[tt][rg] * a_s;
      pd[rg] += acc[tt][rg] * a_d;
    }
  }
  #pragma unroll
  for (int rg = 0; rg < 4; ++rg){
    #pragma unroll
    for (int s = 1; s < 16; s <<= 1){
      ps[rg] += __shfl_xor(ps[rg], s, 64);
      pd[rg] += __shfl_xor(pd[rg], s, 64);
    }
  }
  if (n == 0){
    #pragma unroll
    for (int rg = 0; rg < 4; ++rg){
      atomicAdd(&svp[q * 4 + rg], ps[rg]);
      atomicAdd(&dvp[q * 4 + rg], pd[rg]);
    }
  }
  #pragma unroll
  for (int rg = 0; rg < 4; ++rg){
    int grow = rtile * 16 + q * 4 + rg;
    #pragma unroll
    for (int tt = 0; tt < 2; ++tt)
      Hbf2[(size_t)grow * DD + (wv * 2 + tt) * 16 + n] = f2h(acc[tt][rg]);
  }
  __syncthreads();
  if (tid < 16){ Sv2[rtile * 16 + tid] = svp[tid]; Dv2[rtile * 16 + tid] = dvp[tid]; }
}

// kF: fused agg-layer2 (x2 rows -> LDS) + output projection tile (wave wv -> t=wv).
__global__ __launch_bounds__(256) void kF(const u16* __restrict__ Hbf2,
                                          const float* __restrict__ Sv2, const float* __restrict__ Dv2,
                                          const int* __restrict__ offs, const int* __restrict__ cnt,
                                          const u16* __restrict__ srcs, const float* __restrict__ b2,
                                          const u16* __restrict__ Wfo, const float* __restrict__ bo,
                                          float* __restrict__ out){
  __shared__ __align__(16) u16 Xs[16 * XST];
  __shared__ int   s_i[4][MAXD];
  __shared__ float s_w[4][MAXD];
  int tid = threadIdx.x, wv = tid >> 6, lane = tid & 63;
  int rtile = blockIdx.x;
  #pragma unroll
  for (int k = 0; k < 4; ++k){
    int r = wv * 4 + k;
    agg_node_lds(Hbf2, Sv2, Dv2, offs, cnt, srcs, b2, Xs + r * XST, 0,
                 rtile * 16 + r, lane, s_i[wv], s_w[wv]);
  }
  __syncthreads();
  const uint4* Wg = (const uint4*)Wfo;
  int q = lane >> 4, n = lane & 15;
  f32x4 acc = (f32x4){0.f, 0.f, 0.f, 0.f};
  union F8 { uint4 u; f16x8 v; };
  #pragma unroll
  for (int ks = 0; ks < 4; ++ks){
    F8 a; a.u = *(const uint4*)((const char*)Xs + n * (XST * 2) + ks * 64 + q * 16);
    F8 b; b.u = Wg[(ks * 4 + wv) * 64 + lane];
    acc = __builtin_amdgcn_mfma_f32_16x16x32_f16(a.v, b.v, acc, 0, 0, 0);
  }
  float bt = bo[wv * 16 + n];
  #pragma unroll
  for (int rg = 0; rg < 4; ++rg){
    int grow = rtile * 16 + q * 4 + rg;
    out[(size_t)grow * DYY + wv * 16 + n] = acc[rg] + bt;
  }
}

extern "C" void kernel_launch(void* const* d_in, const int* in_sizes, int n_in,
                              void* d_out, int out_size, void* d_ws, size_t ws_size,
                              hipStream_t stream) {
  const float* node_x = (const float*)d_in[0];
  const int* ei   = (const int*)d_in[1];
  const int* srcp = ei;
  const int* dstp = ei + EE;
  const float* W1  = (const float*)d_in[2];
  const float* as1 = (const float*)d_in[3];
  const float* ad1 = (const float*)d_in[4];
  const float* b1  = (const float*)d_in[5];
  const float* W2  = (const float*)d_in[6];
  const float* as2 = (const float*)d_in[7];
  const float* ad2 = (const float*)d_in[8];
  const float* b2  = (const float*)d_in[9];
  const float* Wo  = (const float*)d_in[10];
  const float* bo  = (const float*)d_in[11];

  // workspace carve: ~34 MB. buf aliases Hbf2 (buf dead after kD; kE writes Hbf2).
  char* w = (char*)d_ws;
  u16*   Hbf1  = (u16*)w;  w += (size_t)NN * DD * 2;  // 12.8 MB layer-1 h (fp16)
  u16*   Hbf2  = (u16*)w;  w += (size_t)NN * DD * 2;  // 12.8 MB layer-2 h (fp16; buf alias)
  u32*   buf   = (u32*)Hbf2;
  float* Sv1   = (float*)w; w += (size_t)NN * 4;
  float* Dv1   = (float*)w; w += (size_t)NN * 4;
  float* Sv2   = (float*)w; w += (size_t)NN * 4;
  float* Dv2   = (float*)w; w += (size_t)NN * 4;
  int*   cnt   = (int*)w;   w += (size_t)NN * 4;
  int*   offs  = (int*)w;   w += (size_t)NN * 4;
  int*   btot  = (int*)w;   w += 1024;
  int*   bbase = (int*)w;   w += 1024;
  int*   hist2d = (int*)w;  w += GB * 256 * 4;        // 200 KB
  u16*   srcs  = (u16*)w;   w += (size_t)EE * 2;      // 3.2 MB
  u16*   Wf1   = (u16*)w;   w += 32768;
  u16*   Wf2   = (u16*)w;   w += 32768;
  u16*   Wfo   = (u16*)w;   w += 16384;

  const int TB = 256;

  kA_prep    <<<216,      TB, 0, stream>>>(dstp, hist2d, W1, W2, Wo, Wf1, Wf2, Wfo);
  kBC        <<<GB + GMM, TB, 0, stream>>>(srcp, dstp, hist2d, btot, bbase, buf,
                                           node_x, Wf1, Hbf1, as1, ad1, Sv1, Dv1);
  kD_finalize<<<NB,       TB, 0, stream>>>(buf, btot, bbase, offs, cnt, srcs);
  kE         <<<NTILE,    TB, 0, stream>>>(Hbf1, Sv1, Dv1, offs, cnt, srcs, b1,
                                           Wf2, as2, ad2, Hbf2, Sv2, Dv2);
  kF         <<<NTILE,    TB, 0, stream>>>(Hbf2, Sv2, Dv2, offs, cnt, srcs, b2,
                                           Wfo, bo, (float*)d_out);
}